// Round 4
// baseline (646.830 us; speedup 1.0000x reference)
//
#include <hip/hip_runtime.h>
#include <hip/hip_bf16.h>

#define NROWS 8192
#define DDIM 768

typedef short short8 __attribute__((ext_vector_type(8)));   // 8 x bf16 (4 VGPRs)
typedef float floatx4 __attribute__((ext_vector_type(4)));  // MFMA C/D
typedef float f4 __attribute__((ext_vector_type(4)));
#define TSTRIDE 132   // transpose LDS row stride (floats): 2-way banks, 16B aligned

// ---------------------------------------------------------------------------
// Kernel 1: row-normalize features (fp32 in) -> bf16 normalized rows
// ---------------------------------------------------------------------------
__global__ __launch_bounds__(256) void normalize_k(const float* __restrict__ f,
                                                   __hip_bfloat16* __restrict__ fn) {
    const int row = blockIdx.x;
    const int t = threadIdx.x;
    const float* fr = f + (size_t)row * DDIM;
    float v0 = fr[t];
    float v1 = fr[t + 256];
    float v2 = fr[t + 512];
    float ss = v0 * v0 + v1 * v1 + v2 * v2;
#pragma unroll
    for (int m = 32; m; m >>= 1) ss += __shfl_xor(ss, m, 64);
    __shared__ float wsum[4];
    if ((t & 63) == 0) wsum[t >> 6] = ss;
    __syncthreads();
    float tot = wsum[0] + wsum[1] + wsum[2] + wsum[3];
    float inv = 1.0f / fmaxf(sqrtf(tot), 1e-8f);
    __hip_bfloat16* o = fn + (size_t)row * DDIM;
    o[t]       = __float2bfloat16(v0 * inv);
    o[t + 256] = __float2bfloat16(v1 * inv);
    o[t + 512] = __float2bfloat16(v2 * inv);
}

// ---------------------------------------------------------------------------
// Kernel 2: SYMMETRIC bf16 GEMM (s = 10 * fn fn^T) + fused mask reductions.
// R12: in-K-loop mask streaming done right (fixing R10/R11's three bugs):
//  (1) 1-iter mask prefetch + counted vmcnt(3): slabs for iter k+1 issued at
//      iter k AFTER the fn loads; the wait drains fn(k)+mask(k) but leaves
//      mask(k+1) in flight across the barrier (~1 iter of latency cover).
//      R11 consumed masks the SAME iter (syncthreads = vmcnt(0) = full HBM
//      latency per iter on the critical path).
//  (2) K-loop fully unrolled: slab decode (side/rg/isN/slot) constant-folds;
//      pack words statically indexed (rule #20).
//  (3) fma-nibble pack (masks are exact 0/1): ~20 VALU/owner vs ~80; slab
//      source-swizzle chunk^=(row&7) makes pack LDS reads structurally
//      conflict-free. Packer thread == consumer thread (derived identity),
//      so the bit layout is exactly R10's verified one.
// Slabs: 64 x 4KB (8 rows x 512B), 3 consumed/iter, 6 live slots (24 KB).
// Diag blocks issue (but don't pack) mirror slabs so vmcnt counts are uniform.
// ---------------------------------------------------------------------------
__global__ __launch_bounds__(256, 4) void ntxent_main(
        const __hip_bfloat16* __restrict__ fn,
        const float* __restrict__ pmask, const float* __restrict__ nmask,
        float* __restrict__ negG, float* __restrict__ sG,
        float* __restrict__ pG) {
    __shared__ __align__(16) char smem[40960];   // fn 16K + 6 mask slots 24K
    __hip_bfloat16* Is = (__hip_bfloat16*)smem;             // [128*32] bf16
    __hip_bfloat16* Js = Is + 128 * 32;
    char* maskLds = smem + 16384;                           // 6 x 4096
    float* T = (float*)smem;                                // mirror transpose alias

    const int t = threadIdx.x;
    const int lane = t & 63;
    const int wv = t >> 6;
    const int wm = wv & 1;           // wave's j-half
    const int wn = wv >> 1;          // wave's i-half
    const int q  = lane >> 4;
    const int cl = lane & 15;

    // XCD-chunked swizzle (2080 = 8*260, bijective)
    const int bt0 = blockIdx.x;
    const int bt = (bt0 & 7) * 260 + (bt0 >> 3);

    // triangular decode: block bt -> (c, r) with c <= r
    int r = (int)((sqrtf(8.0f * (float)bt + 1.0f) - 1.0f) * 0.5f);
    while ((r + 1) * (r + 2) / 2 <= bt) ++r;
    while (r * (r + 1) / 2 > bt) --r;
    const int c = bt - r * (r + 1) / 2;
    const int rowBase = c * 128;     // i-tile
    const int colBase = r * 128;     // j-tile
    const bool offDiag = (c != r);

    const int rdSw = ((q ^ ((cl >> 1) & 3)) << 4);

    // slab DMA per-thread constants: row in slab, source-swizzled chunk
    const int sRow = t >> 5;                        // 0..7
    const int sChunk = (t & 31) ^ (sRow & 7);       // source chunk (pre-swizzled)

    floatx4 acc[4][4];            // [mf (j)][nf (i)]
#pragma unroll
    for (int mf = 0; mf < 4; ++mf)
#pragma unroll
        for (int nf = 0; nf < 4; ++nf)
            acc[mf][nf] = (floatx4){0.f, 0.f, 0.f, 0.f};

    // packed mask words: direct per nf, mirror per st; bits [15:0]=pos [31:16]=neg
    unsigned int dw[4] = {0u, 0u, 0u, 0u};
    unsigned int mw[4] = {0u, 0u, 0u, 0u};

    // slab issue: s in [0,64): side=s>>5 (0 direct,1 mirror), rg=(s&31)>>1, isN=s&1
    auto issue_slab = [&](int s) {
        const int slot = s % 6;
        const int side = s >> 5;
        const int rg   = (s & 31) >> 1;
        const float* mp = (s & 1) ? nmask : pmask;
        const int rowG = (side ? colBase : rowBase) + rg * 8 + sRow;
        const int colG = (side ? rowBase : colBase) + sChunk * 4;
        const float* src = mp + (size_t)rowG * NROWS + colG;
        __builtin_amdgcn_global_load_lds(
            (const __attribute__((address_space(1))) void*)src,
            (__attribute__((address_space(3))) void*)(maskLds + slot * 4096 + t * 16),
            16, 0, 0);
    };

    // pack: nibble = m0+2m1+4m2+8m3 (exact for 0/1); word = sum 16^i * nib_i
    auto pack_slab = [&](int s) {
        const int slot = s % 6;
        const int side = s >> 5;
        const int rg   = (s & 31) >> 1;
        const int sh   = (s & 1) ? 16 : 0;
        if (side == 0) {
            if (wn == (rg >> 3) && (cl >> 3) == (rg & 1)) {
                const int nf = (rg >> 1) & 3;
                const int rl = cl & 7;
                const char* base = maskLds + slot * 4096 + rl * 512;
                float word = 0.f;
#pragma unroll
                for (int mf = 3; mf >= 0; --mf) {
                    const int pos = (wm * 16 + mf * 4 + q) ^ rl;
                    const f4 m = *(const f4*)(base + pos * 16);
                    float nib = fmaf(2.f, m[1], m[0]) + fmaf(8.f, m[3], 4.f * m[2]);
                    word = fmaf(word, 16.f, nib);
                }
                dw[nf] |= ((unsigned int)word) << sh;
            }
        } else if (offDiag) {
            if (wv == (rg & 3)) {
                const int st = rg >> 2;
                const int rl = (t >> 3) & 7;
                const int h  = t & 7;
                const char* base = maskLds + slot * 4096 + rl * 512;
                float word = 0.f;
#pragma unroll
                for (int u = 3; u >= 0; --u) {
                    const int pos = (h * 4 + u) ^ rl;
                    const f4 m = *(const f4*)(base + pos * 16);
                    float nib = fmaf(2.f, m[1], m[0]) + fmaf(8.f, m[3], 4.f * m[2]);
                    word = fmaf(word, 16.f, nib);
                }
                mw[st] |= ((unsigned int)word) << sh;
            }
        }
    };

    // prologue: slabs for iter 0 in flight
    issue_slab(0); issue_slab(1); issue_slab(2);

#pragma unroll
    for (int kt = 0; kt < 24; ++kt) {
        const int k0 = kt * 32;
        // previous iter's LDS readers done before DMA overwrites
        asm volatile("s_waitcnt lgkmcnt(0)\n\ts_barrier" ::: "memory");

        // ---- fn staging (L2/L3-resident), 4 instrs ----
#pragma unroll
        for (int it = 0; it < 2; ++it) {
            const int s = it * 256 + t;              // 16B slot 0..511
            const int rr = s >> 2;
            const int cg = (s & 3) ^ ((rr >> 1) & 3); // swizzled src chunk
            const __hip_bfloat16* ga = fn + (size_t)(rowBase + rr) * DDIM + k0 + cg * 8;
            const __hip_bfloat16* gb = fn + (size_t)(colBase + rr) * DDIM + k0 + cg * 8;
            __builtin_amdgcn_global_load_lds(
                (const __attribute__((address_space(1))) void*)ga,
                (__attribute__((address_space(3))) void*)((char*)Is + s * 16), 16, 0, 0);
            __builtin_amdgcn_global_load_lds(
                (const __attribute__((address_space(1))) void*)gb,
                (__attribute__((address_space(3))) void*)((char*)Js + s * 16), 16, 0, 0);
        }

        // ---- mask prefetch for iter kt+1 (after fn -> fn drains first) ----
#pragma unroll
        for (int gl = 0; gl < 3; ++gl) {
            const int s = 3 * (kt + 1) + gl;
            if (s <= 63) issue_slab(s);
        }

        // drain fn(kt) + mask(kt); leave mask(kt+1) in flight across barrier
        if (kt < 20)       asm volatile("s_waitcnt vmcnt(3)\n\ts_barrier" ::: "memory");
        else if (kt == 20) asm volatile("s_waitcnt vmcnt(1)\n\ts_barrier" ::: "memory");
        else               asm volatile("s_waitcnt vmcnt(0)\n\ts_barrier" ::: "memory");

        // ---- MFMA compute ----
        short8 jf[4], if_[4];
#pragma unroll
        for (int mf = 0; mf < 4; ++mf) {
            const int rr = wm * 64 + mf * 16 + cl;
            jf[mf] = *(const short8*)((const char*)Js + rr * 64 + rdSw);
        }
#pragma unroll
        for (int nf = 0; nf < 4; ++nf) {
            const int rr = wn * 64 + nf * 16 + cl;
            if_[nf] = *(const short8*)((const char*)Is + rr * 64 + rdSw);
        }
#pragma unroll
        for (int mf = 0; mf < 4; ++mf)
#pragma unroll
            for (int nf = 0; nf < 4; ++nf)
                acc[mf][nf] = __builtin_amdgcn_mfma_f32_16x16x32_bf16(
                    jf[mf], if_[nf], acc[mf][nf], 0, 0, 0);

        // ---- pack this iter's slabs (compile-time decode after unroll) ----
#pragma unroll
        for (int gl = 0; gl < 3; ++gl) {
            const int s = 3 * kt + gl;
            if (s <= 63) pack_slab(s);
        }
    }

    // ---- direct epilogue (rows i, mask[i][j]) -- masks from dw bits ----
    const int col64 = colBase + wm * 64;
    const int jb0 = col64 + q * 4;
#pragma unroll
    for (int nf = 0; nf < 4; ++nf) {
        const int grow = rowBase + wn * 64 + nf * 16 + cl;
        const unsigned int w = dw[nf];
        float aN = 0.f, aS = 0.f, aP = 0.f;
#pragma unroll
        for (int mf = 0; mf < 4; ++mf) {
            const int jbase = jb0 + mf * 16;
#pragma unroll
            for (int reg = 0; reg < 4; ++reg) {
                const int b = mf * 4 + reg;
                float pmv = ((w >> b) & 1u) ? 1.0f : 0.0f;
                float nmv = ((w >> (16 + b)) & 1u) ? 1.0f : 0.0f;
                if (grow == jbase + reg) { pmv = 0.f; nmv = 0.f; }  // diagonal
                float v = acc[mf][nf][reg];
                float e = __builtin_amdgcn_exp2f(v * 14.4269504089f); // e^(10v)
                aN = fmaf(nmv, e, aN);
                aS = fmaf(pmv, v, aS);       // raw acc units; x10 in final_k
                aP += pmv;
            }
        }
        aN += __shfl_xor(aN, 16, 64);  aN += __shfl_xor(aN, 32, 64);
        aS += __shfl_xor(aS, 16, 64);  aS += __shfl_xor(aS, 32, 64);
        aP += __shfl_xor(aP, 16, 64);  aP += __shfl_xor(aP, 32, 64);
        if (q == 0) {
            atomicAdd(&negG[grow], aN);
            atomicAdd(&sG[grow],   aS);
            atomicAdd(&pG[grow],   aP);
        }
    }

    // ---- mirror epilogue (rows j, mask[j][i]) -- off-diagonal blocks only --
    if (offDiag) {
        const int jl2 = t >> 3;              // 0..31: strip-local j row
        const int iseg = (t & 7) * 16;       // 16-float i segment
#pragma unroll
        for (int st = 0; st < 4; ++st) {
            __syncthreads();                 // strip buffer free
            if (wm == (st >> 1)) {           // waves owning this strip's j's
#pragma unroll
                for (int m2 = 0; m2 < 2; ++m2) {
                    const int mf = (st & 1) * 2 + m2;
#pragma unroll
                    for (int nf = 0; nf < 4; ++nf) {
                        const int i = wn * 64 + nf * 16 + cl;
#pragma unroll
                        for (int reg = 0; reg < 4; ++reg) {
                            const int jl = m2 * 16 + q * 4 + reg;
                            T[jl * TSTRIDE + i] = acc[mf][nf][reg];
                        }
                    }
                }
            }
            __syncthreads();
            const int jg = colBase + st * 32 + jl2;
            const unsigned int w = mw[st];
            const f4* tv = (const f4*)(T + jl2 * TSTRIDE + iseg);
            float aN = 0.f, aS = 0.f, aP = 0.f;
#pragma unroll
            for (int u = 0; u < 4; ++u) {
                f4 v4 = tv[u];
#pragma unroll
                for (int e = 0; e < 4; ++e) {
                    const int b = u * 4 + e;
                    float v = v4[e];
                    float pmv = ((w >> b) & 1u) ? 1.0f : 0.0f;
                    float nmv = ((w >> (16 + b)) & 1u) ? 1.0f : 0.0f;
                    float ex = __builtin_amdgcn_exp2f(v * 14.4269504089f);
                    aN = fmaf(nmv, ex, aN);
                    aS = fmaf(pmv, v, aS);
                    aP += pmv;
                }
            }
            aN += __shfl_xor(aN, 1, 64); aN += __shfl_xor(aN, 2, 64); aN += __shfl_xor(aN, 4, 64);
            aS += __shfl_xor(aS, 1, 64); aS += __shfl_xor(aS, 2, 64); aS += __shfl_xor(aS, 4, 64);
            aP += __shfl_xor(aP, 1, 64); aP += __shfl_xor(aP, 2, 64); aP += __shfl_xor(aP, 4, 64);
            if ((t & 7) == 0) {
                atomicAdd(&negG[jg], aN);
                atomicAdd(&sG[jg],   aS);
                atomicAdd(&pG[jg],   aP);
            }
        }
    }
}

// ---------------------------------------------------------------------------
// Kernel 3: per-row loss assembly + mean
// loss_i = (P*log(neg) - 10*S_raw)/P (P>0 else 0);  out = mean
// ---------------------------------------------------------------------------
__global__ __launch_bounds__(1024) void final_k(const float* __restrict__ negG,
        const float* __restrict__ sG, const float* __restrict__ pG,
        float* __restrict__ out) {
    const int t = threadIdx.x;
    float sum = 0.f;
    for (int i = t; i < NROWS; i += 1024) {
        float P = pG[i];
        if (P > 0.f) {
            sum += (P * logf(negG[i]) - 10.0f * sG[i]) / P;
        }
    }
#pragma unroll
    for (int m = 32; m; m >>= 1) sum += __shfl_xor(sum, m, 64);
    __shared__ float wsum[16];
    if ((t & 63) == 0) wsum[t >> 6] = sum;
    __syncthreads();
    if (t < 16) {
        float v = wsum[t];
#pragma unroll
        for (int m = 8; m; m >>= 1) v += __shfl_xor(v, m, 16);
        if (t == 0) out[0] = v / (float)NROWS;
    }
}

// ---------------------------------------------------------------------------
extern "C" void kernel_launch(void* const* d_in, const int* in_sizes, int n_in,
                              void* d_out, int out_size, void* d_ws, size_t ws_size,
                              hipStream_t stream) {
    const float* feat  = (const float*)d_in[0];
    const float* pmask = (const float*)d_in[1];
    const float* nmask = (const float*)d_in[2];
    float* out = (float*)d_out;

    char* ws = (char*)d_ws;
    __hip_bfloat16* fn = (__hip_bfloat16*)ws;                    // 12,582,912 B
    float* negG = (float*)(ws + 12582912);
    float* sG = negG + NROWS;
    float* pG = sG + NROWS;

    // zero all three row accumulators (ws is re-poisoned before every launch)
    hipMemsetAsync(negG, 0, 3 * NROWS * sizeof(float), stream);

    normalize_k<<<NROWS, 256, 0, stream>>>(feat, fn);

    ntxent_main<<<2080, 256, 0, stream>>>(fn, pmask, nmask, negG, sG, pG);

    final_k<<<1, 1024, 0, stream>>>(negG, sG, pG, out);
}

// Round 6
// 588.393 us; speedup vs baseline: 1.0993x; 1.0993x over previous
//
#include <hip/hip_runtime.h>
#include <hip/hip_bf16.h>

#define NROWS 8192
#define DDIM 768

typedef short short8 __attribute__((ext_vector_type(8)));   // 8 x bf16 (4 VGPRs)
typedef float floatx4 __attribute__((ext_vector_type(4)));  // MFMA C/D
typedef float f4 __attribute__((ext_vector_type(4)));
#define TSTRIDE 132   // transpose LDS row stride (floats): 2-way banks, 16B aligned

// ---------------------------------------------------------------------------
// Kernel 1: row-normalize features (fp32 in) -> bf16 normalized rows
// ---------------------------------------------------------------------------
__global__ __launch_bounds__(256) void normalize_k(const float* __restrict__ f,
                                                   __hip_bfloat16* __restrict__ fn) {
    const int row = blockIdx.x;
    const int t = threadIdx.x;
    const float* fr = f + (size_t)row * DDIM;
    float v0 = fr[t];
    float v1 = fr[t + 256];
    float v2 = fr[t + 512];
    float ss = v0 * v0 + v1 * v1 + v2 * v2;
#pragma unroll
    for (int m = 32; m; m >>= 1) ss += __shfl_xor(ss, m, 64);
    __shared__ float wsum[4];
    if ((t & 63) == 0) wsum[t >> 6] = ss;
    __syncthreads();
    float tot = wsum[0] + wsum[1] + wsum[2] + wsum[3];
    float inv = 1.0f / fmaxf(sqrtf(tot), 1e-8f);
    __hip_bfloat16* o = fn + (size_t)row * DDIM;
    o[t]       = __float2bfloat16(v0 * inv);
    o[t + 256] = __float2bfloat16(v1 * inv);
    o[t + 512] = __float2bfloat16(v2 * inv);
}

// ---------------------------------------------------------------------------
// Kernel 2: SYMMETRIC bf16 GEMM (s = 10 * fn fn^T) + fused mask reductions.
// R14 = R12's schedule (HW-verified absmax=0) + the spill fix.
// R13's NaN root cause (vmcnt simulation): with depth-2 prefetch the in-order
// vmcnt counter cannot drain fn(kt) without draining masks(kt+1) -- at iter 0
// vmcnt(6) left 3 of 4 fn loads in flight -> MFMA read garbage. Depth-1
// (R12) is the deepest legal pipeline without double-buffering fn.
// Steady-state accounting (verified by simulation): at the wait,
// outstanding = masks(kt) 3 + fn(kt) 4 + masks(kt+1) 3 = 10; vmcnt(3)
// drains exactly masks(kt)+fn(kt), keeps masks(kt+1) in flight across the
// barrier. Tail: kt==20 -> vmcnt(1), kt>=21 -> vmcnt(0).
// Spill fix: __launch_bounds__(256,3). R12's (256,4) forced a 128-reg budget
// and the 24x unroll spilled ~39 regs/thread (WRITE_SIZE 9->90 MB).
// Occupancy was already ~12 waves/CU (38%), so 3 blocks/CU costs nothing.
// Bit layout, fma-nibble pack, swizzles, epilogues: byte-identical to R12.
// ---------------------------------------------------------------------------
__global__ __launch_bounds__(256, 3) void ntxent_main(
        const __hip_bfloat16* __restrict__ fn,
        const float* __restrict__ pmask, const float* __restrict__ nmask,
        float* __restrict__ negG, float* __restrict__ sG,
        float* __restrict__ pG) {
    __shared__ __align__(16) char smem[40960];   // fn 16K + 6 mask slots 24K
    __hip_bfloat16* Is = (__hip_bfloat16*)smem;             // [128*32] bf16
    __hip_bfloat16* Js = Is + 128 * 32;
    char* maskLds = smem + 16384;                           // 6 x 4096
    float* T = (float*)smem;                                // mirror transpose alias

    const int t = threadIdx.x;
    const int lane = t & 63;
    const int wv = t >> 6;
    const int wm = wv & 1;           // wave's j-half
    const int wn = wv >> 1;          // wave's i-half
    const int q  = lane >> 4;
    const int cl = lane & 15;

    // XCD-chunked swizzle (2080 = 8*260, bijective)
    const int bt0 = blockIdx.x;
    const int bt = (bt0 & 7) * 260 + (bt0 >> 3);

    // triangular decode: block bt -> (c, r) with c <= r
    int r = (int)((sqrtf(8.0f * (float)bt + 1.0f) - 1.0f) * 0.5f);
    while ((r + 1) * (r + 2) / 2 <= bt) ++r;
    while (r * (r + 1) / 2 > bt) --r;
    const int c = bt - r * (r + 1) / 2;
    const int rowBase = c * 128;     // i-tile
    const int colBase = r * 128;     // j-tile
    const bool offDiag = (c != r);

    const int rdSw = ((q ^ ((cl >> 1) & 3)) << 4);

    // slab DMA per-thread constants: row in slab, source-swizzled chunk
    const int sRow = t >> 5;                        // 0..7
    const int sChunk = (t & 31) ^ (sRow & 7);       // source chunk (pre-swizzled)

    floatx4 acc[4][4];            // [mf (j)][nf (i)]
#pragma unroll
    for (int mf = 0; mf < 4; ++mf)
#pragma unroll
        for (int nf = 0; nf < 4; ++nf)
            acc[mf][nf] = (floatx4){0.f, 0.f, 0.f, 0.f};

    // packed mask words: direct per nf, mirror per st; bits [15:0]=pos [31:16]=neg
    unsigned int dw[4] = {0u, 0u, 0u, 0u};
    unsigned int mw[4] = {0u, 0u, 0u, 0u};

    // slab issue: s in [0,64): side=s>>5 (0 direct,1 mirror), rg=(s&31)>>1, isN=s&1
    auto issue_slab = [&](int s) {
        const int slot = s % 6;
        const int side = s >> 5;
        const int rg   = (s & 31) >> 1;
        const float* mp = (s & 1) ? nmask : pmask;
        const int rowG = (side ? colBase : rowBase) + rg * 8 + sRow;
        const int colG = (side ? rowBase : colBase) + sChunk * 4;
        const float* src = mp + (size_t)rowG * NROWS + colG;
        __builtin_amdgcn_global_load_lds(
            (const __attribute__((address_space(1))) void*)src,
            (__attribute__((address_space(3))) void*)(maskLds + slot * 4096 + t * 16),
            16, 0, 0);
    };

    // pack: nibble = m0+2m1+4m2+8m3 (exact for 0/1); word = sum 16^i * nib_i
    auto pack_slab = [&](int s) {
        const int slot = s % 6;
        const int side = s >> 5;
        const int rg   = (s & 31) >> 1;
        const int sh   = (s & 1) ? 16 : 0;
        if (side == 0) {
            if (wn == (rg >> 3) && (cl >> 3) == (rg & 1)) {
                const int nf = (rg >> 1) & 3;
                const int rl = cl & 7;
                const char* base = maskLds + slot * 4096 + rl * 512;
                float word = 0.f;
#pragma unroll
                for (int mf = 3; mf >= 0; --mf) {
                    const int pos = (wm * 16 + mf * 4 + q) ^ rl;
                    const f4 m = *(const f4*)(base + pos * 16);
                    float nib = fmaf(2.f, m[1], m[0]) + fmaf(8.f, m[3], 4.f * m[2]);
                    word = fmaf(word, 16.f, nib);
                }
                dw[nf] |= ((unsigned int)word) << sh;
            }
        } else if (offDiag) {
            if (wv == (rg & 3)) {
                const int st = rg >> 2;
                const int rl = (t >> 3) & 7;
                const int h  = t & 7;
                const char* base = maskLds + slot * 4096 + rl * 512;
                float word = 0.f;
#pragma unroll
                for (int u = 3; u >= 0; --u) {
                    const int pos = (h * 4 + u) ^ rl;
                    const f4 m = *(const f4*)(base + pos * 16);
                    float nib = fmaf(2.f, m[1], m[0]) + fmaf(8.f, m[3], 4.f * m[2]);
                    word = fmaf(word, 16.f, nib);
                }
                mw[st] |= ((unsigned int)word) << sh;
            }
        }
    };

    // prologue: slabs for iter 0 in flight (depth 1)
    issue_slab(0); issue_slab(1); issue_slab(2);

#pragma unroll
    for (int kt = 0; kt < 24; ++kt) {
        const int k0 = kt * 32;
        // previous iter's LDS readers done before DMA overwrites
        asm volatile("s_waitcnt lgkmcnt(0)\n\ts_barrier" ::: "memory");

        // ---- fn staging (L2/L3-resident), 4 instrs ----
#pragma unroll
        for (int it = 0; it < 2; ++it) {
            const int s = it * 256 + t;              // 16B slot 0..511
            const int rr = s >> 2;
            const int cg = (s & 3) ^ ((rr >> 1) & 3); // swizzled src chunk
            const __hip_bfloat16* ga = fn + (size_t)(rowBase + rr) * DDIM + k0 + cg * 8;
            const __hip_bfloat16* gb = fn + (size_t)(colBase + rr) * DDIM + k0 + cg * 8;
            __builtin_amdgcn_global_load_lds(
                (const __attribute__((address_space(1))) void*)ga,
                (__attribute__((address_space(3))) void*)((char*)Is + s * 16), 16, 0, 0);
            __builtin_amdgcn_global_load_lds(
                (const __attribute__((address_space(1))) void*)gb,
                (__attribute__((address_space(3))) void*)((char*)Js + s * 16), 16, 0, 0);
        }

        // ---- mask prefetch for iter kt+1 (issued after fn) ----
#pragma unroll
        for (int gl = 0; gl < 3; ++gl) {
            const int s = 3 * (kt + 1) + gl;
            if (s <= 63) issue_slab(s);
        }

        // drain masks(kt)+fn(kt); keep masks(kt+1) in flight across barrier
        if (kt < 20)       asm volatile("s_waitcnt vmcnt(3)\n\ts_barrier" ::: "memory");
        else if (kt == 20) asm volatile("s_waitcnt vmcnt(1)\n\ts_barrier" ::: "memory");
        else               asm volatile("s_waitcnt vmcnt(0)\n\ts_barrier" ::: "memory");

        // ---- MFMA compute ----
        short8 jf[4], if_[4];
#pragma unroll
        for (int mf = 0; mf < 4; ++mf) {
            const int rr = wm * 64 + mf * 16 + cl;
            jf[mf] = *(const short8*)((const char*)Js + rr * 64 + rdSw);
        }
#pragma unroll
        for (int nf = 0; nf < 4; ++nf) {
            const int rr = wn * 64 + nf * 16 + cl;
            if_[nf] = *(const short8*)((const char*)Is + rr * 64 + rdSw);
        }
#pragma unroll
        for (int mf = 0; mf < 4; ++mf)
#pragma unroll
            for (int nf = 0; nf < 4; ++nf)
                acc[mf][nf] = __builtin_amdgcn_mfma_f32_16x16x32_bf16(
                    jf[mf], if_[nf], acc[mf][nf], 0, 0, 0);

        // ---- pack this iter's slabs (compile-time decode after unroll) ----
#pragma unroll
        for (int gl = 0; gl < 3; ++gl) {
            const int s = 3 * kt + gl;
            if (s <= 63) pack_slab(s);
        }
    }

    // ---- direct epilogue (rows i, mask[i][j]) -- masks from dw bits ----
    const int col64 = colBase + wm * 64;
    const int jb0 = col64 + q * 4;
#pragma unroll
    for (int nf = 0; nf < 4; ++nf) {
        const int grow = rowBase + wn * 64 + nf * 16 + cl;
        const unsigned int w = dw[nf];
        float aN = 0.f, aS = 0.f, aP = 0.f;
#pragma unroll
        for (int mf = 0; mf < 4; ++mf) {
            const int jbase = jb0 + mf * 16;
#pragma unroll
            for (int reg = 0; reg < 4; ++reg) {
                const int b = mf * 4 + reg;
                float pmv = ((w >> b) & 1u) ? 1.0f : 0.0f;
                float nmv = ((w >> (16 + b)) & 1u) ? 1.0f : 0.0f;
                if (grow == jbase + reg) { pmv = 0.f; nmv = 0.f; }  // diagonal
                float v = acc[mf][nf][reg];
                float e = __builtin_amdgcn_exp2f(v * 14.4269504089f); // e^(10v)
                aN = fmaf(nmv, e, aN);
                aS = fmaf(pmv, v, aS);       // raw acc units; x10 in final_k
                aP += pmv;
            }
        }
        aN += __shfl_xor(aN, 16, 64);  aN += __shfl_xor(aN, 32, 64);
        aS += __shfl_xor(aS, 16, 64);  aS += __shfl_xor(aS, 32, 64);
        aP += __shfl_xor(aP, 16, 64);  aP += __shfl_xor(aP, 32, 64);
        if (q == 0) {
            atomicAdd(&negG[grow], aN);
            atomicAdd(&sG[grow],   aS);
            atomicAdd(&pG[grow],   aP);
        }
    }

    // ---- mirror epilogue (rows j, mask[j][i]) -- off-diagonal blocks only --
    if (offDiag) {
        const int jl2 = t >> 3;              // 0..31: strip-local j row
        const int iseg = (t & 7) * 16;       // 16-float i segment
#pragma unroll
        for (int st = 0; st < 4; ++st) {
            __syncthreads();                 // strip buffer free
            if (wm == (st >> 1)) {           // waves owning this strip's j's
#pragma unroll
                for (int m2 = 0; m2 < 2; ++m2) {
                    const int mf = (st & 1) * 2 + m2;
#pragma unroll
                    for (int nf = 0; nf < 4; ++nf) {
                        const int i = wn * 64 + nf * 16 + cl;
#pragma unroll
                        for (int reg = 0; reg < 4; ++reg) {
                            const int jl = m2 * 16 + q * 4 + reg;
                            T[jl * TSTRIDE + i] = acc[mf][nf][reg];
                        }
                    }
                }
            }
            __syncthreads();
            const int jg = colBase + st * 32 + jl2;
            const unsigned int w = mw[st];
            const f4* tv = (const f4*)(T + jl2 * TSTRIDE + iseg);
            float aN = 0.f, aS = 0.f, aP = 0.f;
#pragma unroll
            for (int u = 0; u < 4; ++u) {
                f4 v4 = tv[u];
#pragma unroll
                for (int e = 0; e < 4; ++e) {
                    const int b = u * 4 + e;
                    float v = v4[e];
                    float pmv = ((w >> b) & 1u) ? 1.0f : 0.0f;
                    float nmv = ((w >> (16 + b)) & 1u) ? 1.0f : 0.0f;
                    float ex = __builtin_amdgcn_exp2f(v * 14.4269504089f);
                    aN = fmaf(nmv, ex, aN);
                    aS = fmaf(pmv, v, aS);
                    aP += pmv;
                }
            }
            aN += __shfl_xor(aN, 1, 64); aN += __shfl_xor(aN, 2, 64); aN += __shfl_xor(aN, 4, 64);
            aS += __shfl_xor(aS, 1, 64); aS += __shfl_xor(aS, 2, 64); aS += __shfl_xor(aS, 4, 64);
            aP += __shfl_xor(aP, 1, 64); aP += __shfl_xor(aP, 2, 64); aP += __shfl_xor(aP, 4, 64);
            if ((t & 7) == 0) {
                atomicAdd(&negG[jg], aN);
                atomicAdd(&sG[jg],   aS);
                atomicAdd(&pG[jg],   aP);
            }
        }
    }
}

// ---------------------------------------------------------------------------
// Kernel 3: per-row loss assembly + mean
// loss_i = (P*log(neg) - 10*S_raw)/P (P>0 else 0);  out = mean
// ---------------------------------------------------------------------------
__global__ __launch_bounds__(1024) void final_k(const float* __restrict__ negG,
        const float* __restrict__ sG, const float* __restrict__ pG,
        float* __restrict__ out) {
    const int t = threadIdx.x;
    float sum = 0.f;
    for (int i = t; i < NROWS; i += 1024) {
        float P = pG[i];
        if (P > 0.f) {
            sum += (P * logf(negG[i]) - 10.0f * sG[i]) / P;
        }
    }
#pragma unroll
    for (int m = 32; m; m >>= 1) sum += __shfl_xor(sum, m, 64);
    __shared__ float wsum[16];
    if ((t & 63) == 0) wsum[t >> 6] = sum;
    __syncthreads();
    if (t < 16) {
        float v = wsum[t];
#pragma unroll
        for (int m = 8; m; m >>= 1) v += __shfl_xor(v, m, 16);
        if (t == 0) out[0] = v / (float)NROWS;
    }
}

// ---------------------------------------------------------------------------
extern "C" void kernel_launch(void* const* d_in, const int* in_sizes, int n_in,
                              void* d_out, int out_size, void* d_ws, size_t ws_size,
                              hipStream_t stream) {
    const float* feat  = (const float*)d_in[0];
    const float* pmask = (const float*)d_in[1];
    const float* nmask = (const float*)d_in[2];
    float* out = (float*)d_out;

    char* ws = (char*)d_ws;
    __hip_bfloat16* fn = (__hip_bfloat16*)ws;                    // 12,582,912 B
    float* negG = (float*)(ws + 12582912);
    float* sG = negG + NROWS;
    float* pG = sG + NROWS;

    // zero all three row accumulators (ws is re-poisoned before every launch)
    hipMemsetAsync(negG, 0, 3 * NROWS * sizeof(float), stream);

    normalize_k<<<NROWS, 256, 0, stream>>>(feat, fn);

    ntxent_main<<<2080, 256, 0, stream>>>(fn, pmask, nmask, negG, sG, pG);

    final_k<<<1, 1024, 0, stream>>>(negG, sG, pG, out);
}

// Round 7
// 573.618 us; speedup vs baseline: 1.1276x; 1.0258x over previous
//
#include <hip/hip_runtime.h>
#include <hip/hip_bf16.h>

#define NROWS 8192
#define DDIM 768

typedef short short8 __attribute__((ext_vector_type(8)));   // 8 x bf16 (4 VGPRs)
typedef float floatx4 __attribute__((ext_vector_type(4)));  // MFMA C/D
typedef float f4 __attribute__((ext_vector_type(4)));
#define TSTRIDE 132   // transpose LDS row stride (floats): 2-way banks, 16B aligned

// ---------------------------------------------------------------------------
// Kernel 1: row-normalize features (fp32 in) -> bf16 normalized rows
// ---------------------------------------------------------------------------
__global__ __launch_bounds__(256) void normalize_k(const float* __restrict__ f,
                                                   __hip_bfloat16* __restrict__ fn) {
    const int row = blockIdx.x;
    const int t = threadIdx.x;
    const float* fr = f + (size_t)row * DDIM;
    float v0 = fr[t];
    float v1 = fr[t + 256];
    float v2 = fr[t + 512];
    float ss = v0 * v0 + v1 * v1 + v2 * v2;
#pragma unroll
    for (int m = 32; m; m >>= 1) ss += __shfl_xor(ss, m, 64);
    __shared__ float wsum[4];
    if ((t & 63) == 0) wsum[t >> 6] = ss;
    __syncthreads();
    float tot = wsum[0] + wsum[1] + wsum[2] + wsum[3];
    float inv = 1.0f / fmaxf(sqrtf(tot), 1e-8f);
    __hip_bfloat16* o = fn + (size_t)row * DDIM;
    o[t]       = __float2bfloat16(v0 * inv);
    o[t + 256] = __float2bfloat16(v1 * inv);
    o[t + 512] = __float2bfloat16(v2 * inv);
}

// ---------------------------------------------------------------------------
// Kernel 2: SYMMETRIC bf16 GEMM (s = 10 * fn fn^T) + fused mask reductions.
// R15 = R14 (HW-verified absmax=0) + three scheduling fixes, same math:
//  (1) Depth-2 mask prefetch, reordered-legal: m(kt+2) issued AFTER fn(kt);
//      vmcnt(3) drains m(kt+1)+fn(kt) (oldest first), keeps m(kt+2) in
//      flight. Every drained mask group had >=1 iter of flight (R13's bug
//      was draining fn while keeping OLDER groups - impossible; this order
//      is legal). Doubles in-flight mask bytes. 9 LDS slots, 3-way rotation:
//      pack(kt) reads slots A while m(kt+1) lands in B and m(kt+2) writes C;
//      A is reused by m(kt+3) only after the next top lgkm-barrier.
//      Simulated: prologue m(0),m(1) -> vmcnt(3) [drains m(0), keeps m(1)];
//      steady: 3+4+3=10 outstanding -> vmcnt(3); tail kt=19 -> 1, kt>=20 -> 0.
//  (2) pack(kt) moved BEFORE the wait (its slabs were drained at wait(kt-1));
//      its VALU now overlaps fn's L3 latency instead of the post-MFMA tail.
//  (3) Register diet: per-mf jf load (1 J-fragment -> 4 MFMAs) cuts peak
//      fragment regs 32->20, targeting <=128 unified regs (4 waves/SIMD
//      tier; R14's 148 fell to the 2-wave tier -> occupancy 38->29.6%).
// ---------------------------------------------------------------------------
__global__ __launch_bounds__(256, 3) void ntxent_main(
        const __hip_bfloat16* __restrict__ fn,
        const float* __restrict__ pmask, const float* __restrict__ nmask,
        float* __restrict__ negG, float* __restrict__ sG,
        float* __restrict__ pG) {
    __shared__ __align__(16) char smem[53248];   // fn 16K + 9 mask slots 36K
    __hip_bfloat16* Is = (__hip_bfloat16*)smem;             // [128*32] bf16
    __hip_bfloat16* Js = Is + 128 * 32;
    char* maskLds = smem + 16384;                           // 9 x 4096
    float* T = (float*)smem;                                // mirror transpose alias

    const int t = threadIdx.x;
    const int lane = t & 63;
    const int wv = t >> 6;
    const int wm = wv & 1;           // wave's j-half
    const int wn = wv >> 1;          // wave's i-half
    const int q  = lane >> 4;
    const int cl = lane & 15;

    // XCD-chunked swizzle (2080 = 8*260, bijective)
    const int bt0 = blockIdx.x;
    const int bt = (bt0 & 7) * 260 + (bt0 >> 3);

    // triangular decode: block bt -> (c, r) with c <= r
    int r = (int)((sqrtf(8.0f * (float)bt + 1.0f) - 1.0f) * 0.5f);
    while ((r + 1) * (r + 2) / 2 <= bt) ++r;
    while (r * (r + 1) / 2 > bt) --r;
    const int c = bt - r * (r + 1) / 2;
    const int rowBase = c * 128;     // i-tile
    const int colBase = r * 128;     // j-tile
    const bool offDiag = (c != r);

    const int rdSw = ((q ^ ((cl >> 1) & 3)) << 4);

    // slab DMA per-thread constants: row in slab, source-swizzled chunk
    const int sRow = t >> 5;                        // 0..7
    const int sChunk = (t & 31) ^ (sRow & 7);       // source chunk (pre-swizzled)

    floatx4 acc[4][4];            // [mf (j)][nf (i)]
#pragma unroll
    for (int mf = 0; mf < 4; ++mf)
#pragma unroll
        for (int nf = 0; nf < 4; ++nf)
            acc[mf][nf] = (floatx4){0.f, 0.f, 0.f, 0.f};

    // packed mask words: direct per nf, mirror per st; bits [15:0]=pos [31:16]=neg
    unsigned int dw[4] = {0u, 0u, 0u, 0u};
    unsigned int mw[4] = {0u, 0u, 0u, 0u};

    // slab issue: s in [0,64): side=s>>5 (0 direct,1 mirror), rg=(s&31)>>1, isN=s&1
    auto issue_slab = [&](int s) {
        const int slot = s % 9;
        const int side = s >> 5;
        const int rg   = (s & 31) >> 1;
        const float* mp = (s & 1) ? nmask : pmask;
        const int rowG = (side ? colBase : rowBase) + rg * 8 + sRow;
        const int colG = (side ? rowBase : colBase) + sChunk * 4;
        const float* src = mp + (size_t)rowG * NROWS + colG;
        __builtin_amdgcn_global_load_lds(
            (const __attribute__((address_space(1))) void*)src,
            (__attribute__((address_space(3))) void*)(maskLds + slot * 4096 + t * 16),
            16, 0, 0);
    };

    // pack: nibble = m0+2m1+4m2+8m3 (exact for 0/1); word = sum 16^i * nib_i
    auto pack_slab = [&](int s) {
        const int slot = s % 9;
        const int side = s >> 5;
        const int rg   = (s & 31) >> 1;
        const int sh   = (s & 1) ? 16 : 0;
        if (side == 0) {
            if (wn == (rg >> 3) && (cl >> 3) == (rg & 1)) {
                const int nf = (rg >> 1) & 3;
                const int rl = cl & 7;
                const char* base = maskLds + slot * 4096 + rl * 512;
                float word = 0.f;
#pragma unroll
                for (int mf = 3; mf >= 0; --mf) {
                    const int pos = (wm * 16 + mf * 4 + q) ^ rl;
                    const f4 m = *(const f4*)(base + pos * 16);
                    float nib = fmaf(2.f, m[1], m[0]) + fmaf(8.f, m[3], 4.f * m[2]);
                    word = fmaf(word, 16.f, nib);
                }
                dw[nf] |= ((unsigned int)word) << sh;
            }
        } else if (offDiag) {
            if (wv == (rg & 3)) {
                const int st = rg >> 2;
                const int rl = (t >> 3) & 7;
                const int h  = t & 7;
                const char* base = maskLds + slot * 4096 + rl * 512;
                float word = 0.f;
#pragma unroll
                for (int u = 3; u >= 0; --u) {
                    const int pos = (h * 4 + u) ^ rl;
                    const f4 m = *(const f4*)(base + pos * 16);
                    float nib = fmaf(2.f, m[1], m[0]) + fmaf(8.f, m[3], 4.f * m[2]);
                    word = fmaf(word, 16.f, nib);
                }
                mw[st] |= ((unsigned int)word) << sh;
            }
        }
    };

    // prologue: slabs for iters 0 and 1 issued; drain m(0), keep m(1) in flight
    issue_slab(0); issue_slab(1); issue_slab(2);
    issue_slab(3); issue_slab(4); issue_slab(5);
    asm volatile("s_waitcnt vmcnt(3)" ::: "memory");

#pragma unroll
    for (int kt = 0; kt < 24; ++kt) {
        const int k0 = kt * 32;
        // previous iter's LDS readers (fragments + pack) done before DMA overwrites
        asm volatile("s_waitcnt lgkmcnt(0)\n\ts_barrier" ::: "memory");

        // ---- fn staging (L2/L3-resident), 4 instrs ----
#pragma unroll
        for (int it = 0; it < 2; ++it) {
            const int s = it * 256 + t;              // 16B slot 0..511
            const int rr = s >> 2;
            const int cg = (s & 3) ^ ((rr >> 1) & 3); // swizzled src chunk
            const __hip_bfloat16* ga = fn + (size_t)(rowBase + rr) * DDIM + k0 + cg * 8;
            const __hip_bfloat16* gb = fn + (size_t)(colBase + rr) * DDIM + k0 + cg * 8;
            __builtin_amdgcn_global_load_lds(
                (const __attribute__((address_space(1))) void*)ga,
                (__attribute__((address_space(3))) void*)((char*)Is + s * 16), 16, 0, 0);
            __builtin_amdgcn_global_load_lds(
                (const __attribute__((address_space(1))) void*)gb,
                (__attribute__((address_space(3))) void*)((char*)Js + s * 16), 16, 0, 0);
        }

        // ---- mask prefetch for iter kt+2 (after fn -> fn is older in queue) ----
#pragma unroll
        for (int gl = 0; gl < 3; ++gl) {
            const int s = 3 * (kt + 2) + gl;
            if (s <= 63) issue_slab(s);
        }

        // ---- pack this iter's slabs IN THE DMA SHADOW (drained at wait(kt-1)) --
#pragma unroll
        for (int gl = 0; gl < 3; ++gl) {
            const int s = 3 * kt + gl;
            if (s <= 63) pack_slab(s);
        }

        // drain m(kt+1)+fn(kt); keep m(kt+2) in flight across the barrier
        if (kt <= 18)      asm volatile("s_waitcnt vmcnt(3)\n\ts_barrier" ::: "memory");
        else if (kt == 19) asm volatile("s_waitcnt vmcnt(1)\n\ts_barrier" ::: "memory");
        else               asm volatile("s_waitcnt vmcnt(0)\n\ts_barrier" ::: "memory");

        // ---- MFMA compute: per-mf jf load (reduced live registers) ----
        short8 if_[4];
#pragma unroll
        for (int nf = 0; nf < 4; ++nf) {
            const int rr = wn * 64 + nf * 16 + cl;
            if_[nf] = *(const short8*)((const char*)Is + rr * 64 + rdSw);
        }
#pragma unroll
        for (int mf = 0; mf < 4; ++mf) {
            const int rr = wm * 64 + mf * 16 + cl;
            const short8 jf = *(const short8*)((const char*)Js + rr * 64 + rdSw);
#pragma unroll
            for (int nf = 0; nf < 4; ++nf)
                acc[mf][nf] = __builtin_amdgcn_mfma_f32_16x16x32_bf16(
                    jf, if_[nf], acc[mf][nf], 0, 0, 0);
        }
    }

    // ---- direct epilogue (rows i, mask[i][j]) -- masks from dw bits ----
    const int col64 = colBase + wm * 64;
    const int jb0 = col64 + q * 4;
#pragma unroll
    for (int nf = 0; nf < 4; ++nf) {
        const int grow = rowBase + wn * 64 + nf * 16 + cl;
        const unsigned int w = dw[nf];
        float aN = 0.f, aS = 0.f, aP = 0.f;
#pragma unroll
        for (int mf = 0; mf < 4; ++mf) {
            const int jbase = jb0 + mf * 16;
#pragma unroll
            for (int reg = 0; reg < 4; ++reg) {
                const int b = mf * 4 + reg;
                float pmv = ((w >> b) & 1u) ? 1.0f : 0.0f;
                float nmv = ((w >> (16 + b)) & 1u) ? 1.0f : 0.0f;
                if (grow == jbase + reg) { pmv = 0.f; nmv = 0.f; }  // diagonal
                float v = acc[mf][nf][reg];
                float e = __builtin_amdgcn_exp2f(v * 14.4269504089f); // e^(10v)
                aN = fmaf(nmv, e, aN);
                aS = fmaf(pmv, v, aS);       // raw acc units; x10 in final_k
                aP += pmv;
            }
        }
        aN += __shfl_xor(aN, 16, 64);  aN += __shfl_xor(aN, 32, 64);
        aS += __shfl_xor(aS, 16, 64);  aS += __shfl_xor(aS, 32, 64);
        aP += __shfl_xor(aP, 16, 64);  aP += __shfl_xor(aP, 32, 64);
        if (q == 0) {
            atomicAdd(&negG[grow], aN);
            atomicAdd(&sG[grow],   aS);
            atomicAdd(&pG[grow],   aP);
        }
    }

    // ---- mirror epilogue (rows j, mask[j][i]) -- off-diagonal blocks only --
    if (offDiag) {
        const int jl2 = t >> 3;              // 0..31: strip-local j row
        const int iseg = (t & 7) * 16;       // 16-float i segment
#pragma unroll
        for (int st = 0; st < 4; ++st) {
            __syncthreads();                 // strip buffer free
            if (wm == (st >> 1)) {           // waves owning this strip's j's
#pragma unroll
                for (int m2 = 0; m2 < 2; ++m2) {
                    const int mf = (st & 1) * 2 + m2;
#pragma unroll
                    for (int nf = 0; nf < 4; ++nf) {
                        const int i = wn * 64 + nf * 16 + cl;
#pragma unroll
                        for (int reg = 0; reg < 4; ++reg) {
                            const int jl = m2 * 16 + q * 4 + reg;
                            T[jl * TSTRIDE + i] = acc[mf][nf][reg];
                        }
                    }
                }
            }
            __syncthreads();
            const int jg = colBase + st * 32 + jl2;
            const unsigned int w = mw[st];
            const f4* tv = (const f4*)(T + jl2 * TSTRIDE + iseg);
            float aN = 0.f, aS = 0.f, aP = 0.f;
#pragma unroll
            for (int u = 0; u < 4; ++u) {
                f4 v4 = tv[u];
#pragma unroll
                for (int e = 0; e < 4; ++e) {
                    const int b = u * 4 + e;
                    float v = v4[e];
                    float pmv = ((w >> b) & 1u) ? 1.0f : 0.0f;
                    float nmv = ((w >> (16 + b)) & 1u) ? 1.0f : 0.0f;
                    float ex = __builtin_amdgcn_exp2f(v * 14.4269504089f);
                    aN = fmaf(nmv, ex, aN);
                    aS = fmaf(pmv, v, aS);
                    aP += pmv;
                }
            }
            aN += __shfl_xor(aN, 1, 64); aN += __shfl_xor(aN, 2, 64); aN += __shfl_xor(aN, 4, 64);
            aS += __shfl_xor(aS, 1, 64); aS += __shfl_xor(aS, 2, 64); aS += __shfl_xor(aS, 4, 64);
            aP += __shfl_xor(aP, 1, 64); aP += __shfl_xor(aP, 2, 64); aP += __shfl_xor(aP, 4, 64);
            if ((t & 7) == 0) {
                atomicAdd(&negG[jg], aN);
                atomicAdd(&sG[jg],   aS);
                atomicAdd(&pG[jg],   aP);
            }
        }
    }
}

// ---------------------------------------------------------------------------
// Kernel 3: per-row loss assembly + mean
// loss_i = (P*log(neg) - 10*S_raw)/P (P>0 else 0);  out = mean
// ---------------------------------------------------------------------------
__global__ __launch_bounds__(1024) void final_k(const float* __restrict__ negG,
        const float* __restrict__ sG, const float* __restrict__ pG,
        float* __restrict__ out) {
    const int t = threadIdx.x;
    float sum = 0.f;
    for (int i = t; i < NROWS; i += 1024) {
        float P = pG[i];
        if (P > 0.f) {
            sum += (P * logf(negG[i]) - 10.0f * sG[i]) / P;
        }
    }
#pragma unroll
    for (int m = 32; m; m >>= 1) sum += __shfl_xor(sum, m, 64);
    __shared__ float wsum[16];
    if ((t & 63) == 0) wsum[t >> 6] = sum;
    __syncthreads();
    if (t < 16) {
        float v = wsum[t];
#pragma unroll
        for (int m = 8; m; m >>= 1) v += __shfl_xor(v, m, 16);
        if (t == 0) out[0] = v / (float)NROWS;
    }
}

// ---------------------------------------------------------------------------
extern "C" void kernel_launch(void* const* d_in, const int* in_sizes, int n_in,
                              void* d_out, int out_size, void* d_ws, size_t ws_size,
                              hipStream_t stream) {
    const float* feat  = (const float*)d_in[0];
    const float* pmask = (const float*)d_in[1];
    const float* nmask = (const float*)d_in[2];
    float* out = (float*)d_out;

    char* ws = (char*)d_ws;
    __hip_bfloat16* fn = (__hip_bfloat16*)ws;                    // 12,582,912 B
    float* negG = (float*)(ws + 12582912);
    float* sG = negG + NROWS;
    float* pG = sG + NROWS;

    // zero all three row accumulators (ws is re-poisoned before every launch)
    hipMemsetAsync(negG, 0, 3 * NROWS * sizeof(float), stream);

    normalize_k<<<NROWS, 256, 0, stream>>>(feat, fn);

    ntxent_main<<<2080, 256, 0, stream>>>(fn, pmask, nmask, negG, sG, pG);

    final_k<<<1, 1024, 0, stream>>>(negG, sG, pG, out);
}